// Round 2
// baseline (474.963 us; speedup 1.0000x reference)
//
#include <hip/hip_runtime.h>

// Problem constants
#define NB   16
#define CD   512     // C
#define HW0  3136    // HW (valid)
#define HWP  3200    // HW padded to multiple of 128
#define DD   512     // D

typedef _Float16 half8 __attribute__((ext_vector_type(8)));
typedef _Float16 half2v __attribute__((ext_vector_type(2)));
typedef float    floatx4 __attribute__((ext_vector_type(4)));

// ---------------------------------------------------------------------------
// async global->LDS, 16B per lane. LDS dst is wave-uniform base + lane*16.
__device__ __forceinline__ void load_lds16(const _Float16* g, _Float16* l) {
    __builtin_amdgcn_global_load_lds(
        (__attribute__((address_space(1))) void*)g,
        (__attribute__((address_space(3))) void*)l,
        16, 0, 0);
}

// ---------------------------------------------------------------------------
// transpose + cast: batch_flat [N, C, HW] fp32 -> Xt [N, HWP, C] fp16
// tile 64(hw) x 128(c); full-wave 256B coalesced loads, half2 stores.
// hw-tiles 0..48 fully valid (3136 = 49*64), tile 49 all pad -> zeros.
__global__ void transpose_cast_kernel(const float* __restrict__ in,
                                      _Float16* __restrict__ out) {
    __shared__ float tile[128][65];
    const int n  = blockIdx.z;
    const int h0 = blockIdx.x * 64;
    const int c0 = blockIdx.y * 128;
    const int tx = threadIdx.x;      // 64
    const int ty = threadIdx.y;      // 4
    const float* src = in + (long long)n * CD * HW0 + (long long)c0 * HW0 + h0;
    const bool valid = (h0 + tx) < HW0;
#pragma unroll
    for (int i = ty; i < 128; i += 4)
        tile[i][tx] = valid ? src[(long long)i * HW0 + tx] : 0.f;
    __syncthreads();
    _Float16* dst = out + (long long)n * HWP * CD + (long long)h0 * CD + c0;
#pragma unroll
    for (int i = ty; i < 64; i += 4) {
        half2v v = { (_Float16)tile[2 * tx][i], (_Float16)tile[2 * tx + 1][i] };
        *(half2v*)(dst + (long long)i * CD + 2 * tx) = v;
    }
}

// ---------------------------------------------------------------------------
// weight/bias conversion: Wq,Wk -> W2 [1024,512] fp16; Wv -> Wvh [512,512] fp16
__global__ void convert_w_kernel(const float* __restrict__ wq, const float* __restrict__ wk,
                                 const float* __restrict__ wv, const float* __restrict__ bq,
                                 const float* __restrict__ bk,
                                 _Float16* __restrict__ w2, _Float16* __restrict__ wvh,
                                 float* __restrict__ b2) {
    int i = blockIdx.x * 256 + threadIdx.x;
    if (i < CD * DD) {
        w2[i]           = (_Float16)wq[i];
        w2[CD * DD + i] = (_Float16)wk[i];
        wvh[i]          = (_Float16)wv[i];
    }
    if (i < DD) { b2[i] = bq[i]; b2[DD + i] = bk[i]; }
}

// ---------------------------------------------------------------------------
// Tiled MFMA GEMM, B^T convention: C[m][col] = sum_k A[m][k] * B[col][k]
// 1-D grid with XCD-chunked swizzle: block b -> work w = (b&7)*(G/8) + (b>>3)
// so each XCD (round-robin b%8) owns a CONTIGUOUS chunk of the work space.
// ORDER 0: x fastest (share B-tile among x-blocks); ORDER 1: y fastest.
template <int BIAS_MODE, bool OUT_HALF, bool ZERO_PAD, int GX, int GY, int ORDER>
__global__ __launch_bounds__(256, 2)
void gemm_tn(const _Float16* __restrict__ A, const _Float16* __restrict__ B,
             void* __restrict__ Cout, const float* __restrict__ bias,
             int K, int nValid, int ldc,
             long long strideA, long long strideB, long long strideC) {
    constexpr int BM = 128, BN = 128, BK = 32;
    __shared__ _Float16 As[BM * BK];
    __shared__ _Float16 Bs[BN * BK];

    const int tid  = threadIdx.x;
    const int wave = tid >> 6;
    const int lane = tid & 63;

    const int G = gridDim.x;               // GX*GY*GZ, divisible by 8
    const int b = blockIdx.x;
    const int w = (b & 7) * (G >> 3) + (b >> 3);
    int bx, by, bz;
    if (ORDER == 0) { bx = w % GX; int r = w / GX; by = r % GY; bz = r / GY; }
    else            { by = w % GY; int r = w / GY; bx = r % GX; bz = r / GX; }

    const int m0 = bx * BM;
    const int n0 = by * BN;

    const _Float16* Ab = A + (long long)bz * strideA;
    const _Float16* Bb = B + (long long)bz * strideB;

    // staging: each wave fills 32 rows of As and 32 rows of Bs per K-step,
    // via 2 global_load_lds (16 rows = 1024B each).
    const int srow = lane >> 2;        // 0..15
    const int scol = (lane & 3) * 8;   // 0,8,16,24
    const _Float16* ga0 = Ab + (long long)(m0 + wave * 32 + srow) * K + scol;
    const _Float16* ga1 = ga0 + (long long)16 * K;
    const _Float16* gb0 = Bb + (long long)(n0 + wave * 32 + srow) * K + scol;
    const _Float16* gb1 = gb0 + (long long)16 * K;
    _Float16* lA0 = As + (wave * 32) * BK;
    _Float16* lA1 = As + (wave * 32 + 16) * BK;
    _Float16* lB0 = Bs + (wave * 32) * BK;
    _Float16* lB1 = Bs + (wave * 32 + 16) * BK;

    floatx4 acc[4][4];
#pragma unroll
    for (int i = 0; i < 4; i++)
#pragma unroll
        for (int j = 0; j < 4; j++) acc[i][j] = (floatx4)0.0f;

    const int wm = (wave >> 1) * 64, wn = (wave & 1) * 64;
    const int frow = lane & 15;         // fragment row (m or n)
    const int fk   = (lane >> 4) * 8;   // fragment k base

    for (int k0 = 0; k0 < K; k0 += BK) {
        load_lds16(ga0, lA0); load_lds16(ga1, lA1);
        load_lds16(gb0, lB0); load_lds16(gb1, lB1);
        ga0 += BK; ga1 += BK; gb0 += BK; gb1 += BK;
        __syncthreads();

        half8 af[4], bf[4];
#pragma unroll
        for (int t = 0; t < 4; t++)
            af[t] = *(const half8*)(As + (wm + t * 16 + frow) * BK + fk);
#pragma unroll
        for (int t = 0; t < 4; t++)
            bf[t] = *(const half8*)(Bs + (wn + t * 16 + frow) * BK + fk);
#pragma unroll
        for (int mt = 0; mt < 4; mt++)
#pragma unroll
            for (int nt = 0; nt < 4; nt++)
                acc[mt][nt] = __builtin_amdgcn_mfma_f32_16x16x32_f16(
                    af[mt], bf[nt], acc[mt][nt], 0, 0, 0);
        __syncthreads();
    }

    // epilogue: C/D layout col = lane&15, row = (lane>>4)*4 + reg
    const int erow = (lane >> 4) * 4;
    const int ecol = lane & 15;
#pragma unroll
    for (int mt = 0; mt < 4; mt++) {
#pragma unroll
        for (int r = 0; r < 4; r++) {
            const int row = m0 + wm + mt * 16 + erow + r;
#pragma unroll
            for (int nt = 0; nt < 4; nt++) {
                const int col = n0 + wn + nt * 16 + ecol;
                float v = acc[mt][nt][r];
                if (BIAS_MODE == 1) v += bias[row];
                if (BIAS_MODE == 2) v += bias[col];
                const bool valid = (col < nValid);
                const long long idx = (long long)bz * strideC + (long long)row * ldc + col;
                if (OUT_HALF) {
                    if (ZERO_PAD) {
                        ((_Float16*)Cout)[idx] = (_Float16)(valid ? v : 0.f);
                    } else if (valid) {
                        ((_Float16*)Cout)[idx] = (_Float16)v;
                    }
                } else {
                    if (ZERO_PAD) {
                        ((float*)Cout)[idx] = valid ? v : 0.f;
                    } else if (valid) {
                        ((float*)Cout)[idx] = v;
                    }
                }
            }
        }
    }
}

// ---------------------------------------------------------------------------
// row softmax: S [16*512 rows x 512] fp32 -> att fp16, one wave per row
__global__ void softmax_kernel(const float* __restrict__ S, _Float16* __restrict__ att) {
    const int row  = blockIdx.x * 4 + (threadIdx.x >> 6);
    const int lane = threadIdx.x & 63;
    const float* src = S + (long long)row * DD;
    float v[8];
#pragma unroll
    for (int i = 0; i < 8; i++) v[i] = src[lane + i * 64];
    float m = v[0];
#pragma unroll
    for (int i = 1; i < 8; i++) m = fmaxf(m, v[i]);
#pragma unroll
    for (int off = 32; off; off >>= 1) m = fmaxf(m, __shfl_xor(m, off, 64));
    float s = 0.f;
#pragma unroll
    for (int i = 0; i < 8; i++) { v[i] = __expf(v[i] - m); s += v[i]; }
#pragma unroll
    for (int off = 32; off; off >>= 1) s += __shfl_xor(s, off, 64);
    const float inv = 1.0f / s;
    _Float16* dst = att + (long long)row * DD;
#pragma unroll
    for (int i = 0; i < 8; i++) dst[lane + i * 64] = (_Float16)(v[i] * inv);
}

// ---------------------------------------------------------------------------
extern "C" void kernel_launch(void* const* d_in, const int* in_sizes, int n_in,
                              void* d_out, int out_size, void* d_ws, size_t ws_size,
                              hipStream_t stream) {
    const float* batch = (const float*)d_in[0];
    const float* Wq = (const float*)d_in[1];
    const float* bq = (const float*)d_in[2];
    const float* Wk = (const float*)d_in[3];
    const float* bk = (const float*)d_in[4];
    const float* Wv = (const float*)d_in[5];
    const float* bv = (const float*)d_in[6];

    char* ws = (char*)d_ws;
    const long long XT_B  = (long long)NB * HWP * CD * 2;      // 52,428,800
    const long long QKT_B = (long long)NB * 2 * DD * HWP * 2;  // 104,857,600
    const long long VS_B  = (long long)NB * HWP * DD * 2;      // 52,428,800
    const long long W2_B  = (long long)2 * DD * CD * 2;        // 1,048,576
    const long long WVH_B = (long long)DD * CD * 2;            // 524,288

    _Float16* Xt  = (_Float16*)(ws);
    _Float16* QKt = (_Float16*)(ws + XT_B);
    _Float16* Vs  = (_Float16*)(ws + XT_B + QKT_B);
    _Float16* W2  = (_Float16*)(ws + XT_B + QKT_B + VS_B);
    _Float16* Wvh = (_Float16*)(ws + XT_B + QKT_B + VS_B + W2_B);
    float*    b2  = (float*)   (ws + XT_B + QKT_B + VS_B + W2_B + WVH_B);
    // S and att alias the Xt region (Xt is dead after the V projection)
    float*    S   = (float*)(ws);
    _Float16* att = (_Float16*)(ws + (long long)NB * DD * DD * 4);

    // 1) weights/bias -> fp16
    convert_w_kernel<<<dim3((CD * DD + 255) / 256), dim3(256), 0, stream>>>(
        Wq, Wk, Wv, bq, bk, W2, Wvh, b2);

    // 2) batch_flat [N,C,HW] fp32 -> Xt [N,HWP,C] fp16 (zero-padded rows)
    transpose_cast_kernel<<<dim3(HWP / 64, CD / 128, NB), dim3(64, 4), 0, stream>>>(
        batch, Xt);

    // 3) QK projection: QKt[n][m][s] = sum_c W2[m][c]*Xt[n][s][c] + b2[m]
    //    GX=8 (m), GY=25 (s), x fastest: x-blocks share the streamed Xt tile.
    gemm_tn<1, true, true, 8, 25, 0><<<dim3(8 * 25 * NB), dim3(256), 0, stream>>>(
        W2, Xt, (void*)QKt, b2, CD, HW0, HWP,
        0LL, (long long)HWP * CD, (long long)2 * DD * HWP);

    // 4) V projection: Vs[n][s][e] = sum_c Xt[n][s][c]*Wv[e][c] + bv[e]
    //    GX=25 (s), GY=4 (e), y fastest: y-blocks share the streamed Xt tile.
    gemm_tn<2, true, false, 25, 4, 1><<<dim3(25 * 4 * NB), dim3(256), 0, stream>>>(
        Xt, Wvh, (void*)Vs, bv, CD, DD, DD,
        (long long)HWP * CD, 0LL, (long long)HWP * DD);

    // 5) scores: S[n][d][e] = sum_s Qt[d][s]*Kt[e][s], K = HWP (pads are 0)
    //    GX=4, GY=4, x fastest; chunking keeps each XCD on ~2 batches.
    gemm_tn<0, false, false, 4, 4, 0><<<dim3(4 * 4 * NB), dim3(256), 0, stream>>>(
        QKt, QKt + (long long)DD * HWP, (void*)S, nullptr, HWP, DD, DD,
        (long long)2 * DD * HWP, (long long)2 * DD * HWP, (long long)DD * DD);

    // 6) softmax rows -> att fp16
    softmax_kernel<<<dim3(NB * DD / 4), dim3(256), 0, stream>>>(S, att);

    // 7) out[n][d][s] = sum_e att[d][e]*Vs[n][s][e] -> d_out [N,D,HW] fp32
    //    GX=4 (d), GY=25 (s), x fastest: x-blocks share the streamed Vs tile.
    gemm_tn<0, false, false, 4, 25, 0><<<dim3(4 * 25 * NB), dim3(256), 0, stream>>>(
        att, Vs, d_out, nullptr, DD, HW0, HW0,
        (long long)DD * DD, (long long)HWP * DD, (long long)DD * HW0);
}

// Round 3
// 473.201 us; speedup vs baseline: 1.0037x; 1.0037x over previous
//
#include <hip/hip_runtime.h>

// Problem constants
#define NB   16
#define CD   512     // C
#define HW0  3136    // HW (valid)
#define HWP  3200    // HW padded to multiple of 128
#define DD   512     // D

typedef _Float16 half8 __attribute__((ext_vector_type(8)));
typedef _Float16 half2v __attribute__((ext_vector_type(2)));
typedef float    floatx4 __attribute__((ext_vector_type(4)));

// ---------------------------------------------------------------------------
// async global->LDS, 16B per lane. LDS dst is wave-uniform base + lane*16.
__device__ __forceinline__ void load_lds16(const _Float16* g, _Float16* l) {
    __builtin_amdgcn_global_load_lds(
        (__attribute__((address_space(1))) void*)g,
        (__attribute__((address_space(3))) void*)l,
        16, 0, 0);
}

// ---------------------------------------------------------------------------
// transpose + cast: batch_flat [N, C, HW] fp32 -> Xt [N, HWP, C] fp16
// tile 64(hw) x 128(c). Loops have COMPILE-TIME trip counts so they fully
// unroll -> ~32 outstanding global loads per thread (R2's rolled loop had 1).
__global__ __launch_bounds__(256) void transpose_cast_kernel(
        const float* __restrict__ in, _Float16* __restrict__ out) {
    __shared__ float tile[128][65];
    const int n  = blockIdx.z;
    const int h0 = blockIdx.x * 64;
    const int c0 = blockIdx.y * 128;
    const int tx = threadIdx.x & 63;
    const int ty = threadIdx.x >> 6;   // wave id 0..3
    const float* src = in + (long long)n * CD * HW0 + (long long)c0 * HW0 + h0;
    const bool valid = (h0 + tx) < HW0;
    // wave ty loads c-rows [32*ty, 32*ty+32); 64 contiguous floats per row
#pragma unroll
    for (int j = 0; j < 32; j++) {
        const int i = ty * 32 + j;
        tile[i][tx] = valid ? src[(long long)i * HW0 + tx] : 0.f;
    }
    __syncthreads();
    _Float16* dst = out + (long long)n * HWP * CD + (long long)h0 * CD + c0;
    // wave ty stores hw-rows [16*ty, 16*ty+16); 128 halves (half2/lane) per row
#pragma unroll
    for (int j = 0; j < 16; j++) {
        const int i = ty * 16 + j;
        half2v v = { (_Float16)tile[2 * tx][i], (_Float16)tile[2 * tx + 1][i] };
        *(half2v*)(dst + (long long)i * CD + 2 * tx) = v;
    }
}

// ---------------------------------------------------------------------------
// weight/bias conversion: Wq,Wk -> W2 [1024,512] fp16; Wv -> Wvh [512,512] fp16
__global__ void convert_w_kernel(const float* __restrict__ wq, const float* __restrict__ wk,
                                 const float* __restrict__ wv, const float* __restrict__ bq,
                                 const float* __restrict__ bk,
                                 _Float16* __restrict__ w2, _Float16* __restrict__ wvh,
                                 float* __restrict__ b2) {
    int i = blockIdx.x * 256 + threadIdx.x;
    if (i < CD * DD) {
        w2[i]           = (_Float16)wq[i];
        w2[CD * DD + i] = (_Float16)wk[i];
        wvh[i]          = (_Float16)wv[i];
    }
    if (i < DD) { b2[i] = bq[i]; b2[DD + i] = bk[i]; }
}

// ---------------------------------------------------------------------------
// Tiled MFMA GEMM, B^T convention: C[m][col] = sum_k A[m][k] * B[col][k]
// 1-D grid with XCD-chunked swizzle: block b -> work w = (b&7)*(G/8) + (b>>3)
// so each XCD (round-robin b%8) owns a CONTIGUOUS chunk of the work space.
// ORDER 0: x fastest (share B-tile among x-blocks); ORDER 1: y fastest.
template <int BIAS_MODE, bool OUT_HALF, bool ZERO_PAD, int GX, int GY, int ORDER>
__global__ __launch_bounds__(256, 2)
void gemm_tn(const _Float16* __restrict__ A, const _Float16* __restrict__ B,
             void* __restrict__ Cout, const float* __restrict__ bias,
             int K, int nValid, int ldc,
             long long strideA, long long strideB, long long strideC) {
    constexpr int BM = 128, BN = 128, BK = 32;
    __shared__ _Float16 As[BM * BK];
    __shared__ _Float16 Bs[BN * BK];

    const int tid  = threadIdx.x;
    const int wave = tid >> 6;
    const int lane = tid & 63;

    const int G = gridDim.x;               // GX*GY*GZ, divisible by 8
    const int b = blockIdx.x;
    const int w = (b & 7) * (G >> 3) + (b >> 3);
    int bx, by, bz;
    if (ORDER == 0) { bx = w % GX; int r = w / GX; by = r % GY; bz = r / GY; }
    else            { by = w % GY; int r = w / GY; bx = r % GX; bz = r / GX; }

    const int m0 = bx * BM;
    const int n0 = by * BN;

    const _Float16* Ab = A + (long long)bz * strideA;
    const _Float16* Bb = B + (long long)bz * strideB;

    const int srow = lane >> 2;        // 0..15
    const int scol = (lane & 3) * 8;   // 0,8,16,24
    const _Float16* ga0 = Ab + (long long)(m0 + wave * 32 + srow) * K + scol;
    const _Float16* ga1 = ga0 + (long long)16 * K;
    const _Float16* gb0 = Bb + (long long)(n0 + wave * 32 + srow) * K + scol;
    const _Float16* gb1 = gb0 + (long long)16 * K;
    _Float16* lA0 = As + (wave * 32) * BK;
    _Float16* lA1 = As + (wave * 32 + 16) * BK;
    _Float16* lB0 = Bs + (wave * 32) * BK;
    _Float16* lB1 = Bs + (wave * 32 + 16) * BK;

    floatx4 acc[4][4];
#pragma unroll
    for (int i = 0; i < 4; i++)
#pragma unroll
        for (int j = 0; j < 4; j++) acc[i][j] = (floatx4)0.0f;

    const int wm = (wave >> 1) * 64, wn = (wave & 1) * 64;
    const int frow = lane & 15;         // fragment row (m or n)
    const int fk   = (lane >> 4) * 8;   // fragment k base

    for (int k0 = 0; k0 < K; k0 += BK) {
        load_lds16(ga0, lA0); load_lds16(ga1, lA1);
        load_lds16(gb0, lB0); load_lds16(gb1, lB1);
        ga0 += BK; ga1 += BK; gb0 += BK; gb1 += BK;
        __syncthreads();

        half8 af[4], bf[4];
#pragma unroll
        for (int t = 0; t < 4; t++)
            af[t] = *(const half8*)(As + (wm + t * 16 + frow) * BK + fk);
#pragma unroll
        for (int t = 0; t < 4; t++)
            bf[t] = *(const half8*)(Bs + (wn + t * 16 + frow) * BK + fk);
#pragma unroll
        for (int mt = 0; mt < 4; mt++)
#pragma unroll
            for (int nt = 0; nt < 4; nt++)
                acc[mt][nt] = __builtin_amdgcn_mfma_f32_16x16x32_f16(
                    af[mt], bf[nt], acc[mt][nt], 0, 0, 0);
        __syncthreads();
    }

    // epilogue: C/D layout col = lane&15, row = (lane>>4)*4 + reg
    const int erow = (lane >> 4) * 4;
    const int ecol = lane & 15;
#pragma unroll
    for (int mt = 0; mt < 4; mt++) {
#pragma unroll
        for (int r = 0; r < 4; r++) {
            const int row = m0 + wm + mt * 16 + erow + r;
#pragma unroll
            for (int nt = 0; nt < 4; nt++) {
                const int col = n0 + wn + nt * 16 + ecol;
                float v = acc[mt][nt][r];
                if (BIAS_MODE == 1) v += bias[row];
                if (BIAS_MODE == 2) v += bias[col];
                const bool valid = (col < nValid);
                const long long idx = (long long)bz * strideC + (long long)row * ldc + col;
                if (OUT_HALF) {
                    if (ZERO_PAD) {
                        ((_Float16*)Cout)[idx] = (_Float16)(valid ? v : 0.f);
                    } else if (valid) {
                        ((_Float16*)Cout)[idx] = (_Float16)v;
                    }
                } else {
                    if (ZERO_PAD) {
                        ((float*)Cout)[idx] = valid ? v : 0.f;
                    } else if (valid) {
                        ((float*)Cout)[idx] = v;
                    }
                }
            }
        }
    }
}

// ---------------------------------------------------------------------------
// row softmax: S [16*512 rows x 512] fp32 -> att fp16, one wave per row
__global__ void softmax_kernel(const float* __restrict__ S, _Float16* __restrict__ att) {
    const int row  = blockIdx.x * 4 + (threadIdx.x >> 6);
    const int lane = threadIdx.x & 63;
    const float* src = S + (long long)row * DD;
    float v[8];
#pragma unroll
    for (int i = 0; i < 8; i++) v[i] = src[lane + i * 64];
    float m = v[0];
#pragma unroll
    for (int i = 1; i < 8; i++) m = fmaxf(m, v[i]);
#pragma unroll
    for (int off = 32; off; off >>= 1) m = fmaxf(m, __shfl_xor(m, off, 64));
    float s = 0.f;
#pragma unroll
    for (int i = 0; i < 8; i++) { v[i] = __expf(v[i] - m); s += v[i]; }
#pragma unroll
    for (int off = 32; off; off >>= 1) s += __shfl_xor(s, off, 64);
    const float inv = 1.0f / s;
    _Float16* dst = att + (long long)row * DD;
#pragma unroll
    for (int i = 0; i < 8; i++) dst[lane + i * 64] = (_Float16)(v[i] * inv);
}

// ---------------------------------------------------------------------------
extern "C" void kernel_launch(void* const* d_in, const int* in_sizes, int n_in,
                              void* d_out, int out_size, void* d_ws, size_t ws_size,
                              hipStream_t stream) {
    const float* batch = (const float*)d_in[0];
    const float* Wq = (const float*)d_in[1];
    const float* bq = (const float*)d_in[2];
    const float* Wk = (const float*)d_in[3];
    const float* bk = (const float*)d_in[4];
    const float* Wv = (const float*)d_in[5];
    const float* bv = (const float*)d_in[6];

    char* ws = (char*)d_ws;
    const long long XT_B  = (long long)NB * HWP * CD * 2;      // 52,428,800
    const long long QKT_B = (long long)NB * 2 * DD * HWP * 2;  // 104,857,600
    const long long VS_B  = (long long)NB * HWP * DD * 2;      // 52,428,800
    const long long W2_B  = (long long)2 * DD * CD * 2;        // 1,048,576
    const long long WVH_B = (long long)DD * CD * 2;            // 524,288

    _Float16* Xt  = (_Float16*)(ws);
    _Float16* QKt = (_Float16*)(ws + XT_B);
    _Float16* Vs  = (_Float16*)(ws + XT_B + QKT_B);
    _Float16* W2  = (_Float16*)(ws + XT_B + QKT_B + VS_B);
    _Float16* Wvh = (_Float16*)(ws + XT_B + QKT_B + VS_B + W2_B);
    float*    b2  = (float*)   (ws + XT_B + QKT_B + VS_B + W2_B + WVH_B);
    // S and att alias the Xt region (Xt is dead after the V projection)
    float*    S   = (float*)(ws);
    _Float16* att = (_Float16*)(ws + (long long)NB * DD * DD * 4);

    // 1) weights/bias -> fp16
    convert_w_kernel<<<dim3((CD * DD + 255) / 256), dim3(256), 0, stream>>>(
        Wq, Wk, Wv, bq, bk, W2, Wvh, b2);

    // 2) batch_flat [N,C,HW] fp32 -> Xt [N,HWP,C] fp16 (zero-padded rows)
    transpose_cast_kernel<<<dim3(HWP / 64, CD / 128, NB), dim3(256), 0, stream>>>(
        batch, Xt);

    // 3) QK projection: QKt[n][m][s] = sum_c W2[m][c]*Xt[n][s][c] + b2[m]
    //    GX=8 (m), GY=25 (s), x fastest: x-blocks share the streamed Xt tile.
    gemm_tn<1, true, true, 8, 25, 0><<<dim3(8 * 25 * NB), dim3(256), 0, stream>>>(
        W2, Xt, (void*)QKt, b2, CD, HW0, HWP,
        0LL, (long long)HWP * CD, (long long)2 * DD * HWP);

    // 4) V projection: Vs[n][s][e] = sum_c Xt[n][s][c]*Wv[e][c] + bv[e]
    //    GX=25 (s), GY=4 (e), y fastest: y-blocks share the streamed Xt tile.
    gemm_tn<2, true, false, 25, 4, 1><<<dim3(25 * 4 * NB), dim3(256), 0, stream>>>(
        Xt, Wvh, (void*)Vs, bv, CD, DD, DD,
        (long long)HWP * CD, 0LL, (long long)HWP * DD);

    // 5) scores: S[n][d][e] = sum_s Qt[d][s]*Kt[e][s], K = HWP (pads are 0)
    gemm_tn<0, false, false, 4, 4, 0><<<dim3(4 * 4 * NB), dim3(256), 0, stream>>>(
        QKt, QKt + (long long)DD * HWP, (void*)S, nullptr, HWP, DD, DD,
        (long long)2 * DD * HWP, (long long)2 * DD * HWP, (long long)DD * DD);

    // 6) softmax rows -> att fp16
    softmax_kernel<<<dim3(NB * DD / 4), dim3(256), 0, stream>>>(S, att);

    // 7) out[n][d][s] = sum_e att[d][e]*Vs[n][s][e] -> d_out [N,D,HW] fp32
    //    GX=4 (d), GY=25 (s), x fastest: x-blocks share the streamed Vs tile.
    gemm_tn<0, false, false, 4, 25, 0><<<dim3(4 * 25 * NB), dim3(256), 0, stream>>>(
        att, Vs, d_out, nullptr, DD, HW0, HW0,
        (long long)DD * DD, (long long)HWP * DD, (long long)DD * HW0);
}

// Round 4
// 439.826 us; speedup vs baseline: 1.0799x; 1.0759x over previous
//
#include <hip/hip_runtime.h>

// Problem constants
#define NB   16
#define CD   512     // C
#define HW0  3136    // HW (valid)
#define HWP  3200    // HW padded to multiple of 128
#define DD   512     // D

typedef _Float16 half8 __attribute__((ext_vector_type(8)));
typedef _Float16 half2v __attribute__((ext_vector_type(2)));
typedef float    floatx4 __attribute__((ext_vector_type(4)));

// ---------------------------------------------------------------------------
// async global->LDS, 16B per lane. LDS dst is wave-uniform base + lane*16.
__device__ __forceinline__ void load_lds16(const _Float16* g, _Float16* l) {
    __builtin_amdgcn_global_load_lds(
        (__attribute__((address_space(1))) void*)g,
        (__attribute__((address_space(3))) void*)l,
        16, 0, 0);
}

// ---------------------------------------------------------------------------
// transpose + cast: batch_flat [N, C, HW] fp32 -> Xt [N, HWP, C] fp16
// tile 64(hw) x 128(c). Read phase: float4/lane (dwordx4), 4 c-rows per
// wave-instruction, 8 insts/thread with 32 VGPRs of payload -> ~8 outstanding
// 1KB requests per wave (R3 had ~1 outstanding 256B load -> 135 cyc/load).
// 3136 = 49*64 so validity is block-uniform (tile x=49 is all pad -> zeros).
__global__ __launch_bounds__(256) void transpose_cast_kernel(
        const float* __restrict__ in, _Float16* __restrict__ out) {
    __shared__ float tile[128][65];
    const int n  = blockIdx.z;
    const int h0 = blockIdx.x * 64;
    const int c0 = blockIdx.y * 128;
    const int t    = threadIdx.x;
    const int lane = t & 63;
    const int w    = t >> 6;           // wave 0..3
    const int rsub = lane >> 4;        // 0..3
    const int col4 = (lane & 15) * 4;  // 0..60 (16B-aligned)
    const float* src = in + (long long)n * CD * HW0 + (long long)c0 * HW0 + h0;
    const bool valid = h0 < HW0;       // block-uniform

    float4 r[8];
    if (valid) {
#pragma unroll
        for (int j = 0; j < 8; j++) {
            const int row = w * 32 + j * 4 + rsub;   // c-row 0..127
            r[j] = *(const float4*)(src + (long long)row * HW0 + col4);
        }
    } else {
#pragma unroll
        for (int j = 0; j < 8; j++) r[j] = make_float4(0.f, 0.f, 0.f, 0.f);
    }
#pragma unroll
    for (int j = 0; j < 8; j++) {
        const int row = w * 32 + j * 4 + rsub;
        tile[row][col4 + 0] = r[j].x;
        tile[row][col4 + 1] = r[j].y;
        tile[row][col4 + 2] = r[j].z;
        tile[row][col4 + 3] = r[j].w;
    }
    __syncthreads();
    _Float16* dst = out + (long long)n * HWP * CD + (long long)h0 * CD + c0;
#pragma unroll
    for (int j = 0; j < 16; j++) {
        const int i = w * 16 + j;      // hw-row 0..63
        half2v v = { (_Float16)tile[2 * lane][i], (_Float16)tile[2 * lane + 1][i] };
        *(half2v*)(dst + (long long)i * CD + 2 * lane) = v;
    }
}

// ---------------------------------------------------------------------------
// weight/bias conversion: Wq,Wk -> W2 [1024,512] fp16; Wv -> Wvh [512,512] fp16
__global__ void convert_w_kernel(const float* __restrict__ wq, const float* __restrict__ wk,
                                 const float* __restrict__ wv, const float* __restrict__ bq,
                                 const float* __restrict__ bk,
                                 _Float16* __restrict__ w2, _Float16* __restrict__ wvh,
                                 float* __restrict__ b2) {
    int i = blockIdx.x * 256 + threadIdx.x;
    if (i < CD * DD) {
        w2[i]           = (_Float16)wq[i];
        w2[CD * DD + i] = (_Float16)wk[i];
        wvh[i]          = (_Float16)wv[i];
    }
    if (i < DD) { b2[i] = bq[i]; b2[DD + i] = bk[i]; }
}

// ---------------------------------------------------------------------------
// Tiled MFMA GEMM, B^T convention: C[m][col] = sum_k A[m][k] * B[col][k]
// 1-D grid with XCD-chunked swizzle: block b -> work w = (b&7)*(G/8) + (b>>3)
// so each XCD (round-robin b%8) owns a CONTIGUOUS chunk of the work space.
// ORDER 0: x fastest (share B-tile among x-blocks); ORDER 1: y fastest.
template <int BIAS_MODE, bool OUT_HALF, bool ZERO_PAD, int GX, int GY, int ORDER>
__global__ __launch_bounds__(256, 2)
void gemm_tn(const _Float16* __restrict__ A, const _Float16* __restrict__ B,
             void* __restrict__ Cout, const float* __restrict__ bias,
             int K, int nValid, int ldc,
             long long strideA, long long strideB, long long strideC) {
    constexpr int BM = 128, BN = 128, BK = 32;
    __shared__ _Float16 As[BM * BK];
    __shared__ _Float16 Bs[BN * BK];

    const int tid  = threadIdx.x;
    const int wave = tid >> 6;
    const int lane = tid & 63;

    const int G = gridDim.x;               // GX*GY*GZ, divisible by 8
    const int b = blockIdx.x;
    const int w = (b & 7) * (G >> 3) + (b >> 3);
    int bx, by, bz;
    if (ORDER == 0) { bx = w % GX; int r = w / GX; by = r % GY; bz = r / GY; }
    else            { by = w % GY; int r = w / GY; bx = r % GX; bz = r / GX; }

    const int m0 = bx * BM;
    const int n0 = by * BN;

    const _Float16* Ab = A + (long long)bz * strideA;
    const _Float16* Bb = B + (long long)bz * strideB;

    const int srow = lane >> 2;        // 0..15
    const int scol = (lane & 3) * 8;   // 0,8,16,24
    const _Float16* ga0 = Ab + (long long)(m0 + wave * 32 + srow) * K + scol;
    const _Float16* ga1 = ga0 + (long long)16 * K;
    const _Float16* gb0 = Bb + (long long)(n0 + wave * 32 + srow) * K + scol;
    const _Float16* gb1 = gb0 + (long long)16 * K;
    _Float16* lA0 = As + (wave * 32) * BK;
    _Float16* lA1 = As + (wave * 32 + 16) * BK;
    _Float16* lB0 = Bs + (wave * 32) * BK;
    _Float16* lB1 = Bs + (wave * 32 + 16) * BK;

    floatx4 acc[4][4];
#pragma unroll
    for (int i = 0; i < 4; i++)
#pragma unroll
        for (int j = 0; j < 4; j++) acc[i][j] = (floatx4)0.0f;

    const int wm = (wave >> 1) * 64, wn = (wave & 1) * 64;
    const int frow = lane & 15;         // fragment row (m or n)
    const int fk   = (lane >> 4) * 8;   // fragment k base

    for (int k0 = 0; k0 < K; k0 += BK) {
        load_lds16(ga0, lA0); load_lds16(ga1, lA1);
        load_lds16(gb0, lB0); load_lds16(gb1, lB1);
        ga0 += BK; ga1 += BK; gb0 += BK; gb1 += BK;
        __syncthreads();

        half8 af[4], bf[4];
#pragma unroll
        for (int t = 0; t < 4; t++)
            af[t] = *(const half8*)(As + (wm + t * 16 + frow) * BK + fk);
#pragma unroll
        for (int t = 0; t < 4; t++)
            bf[t] = *(const half8*)(Bs + (wn + t * 16 + frow) * BK + fk);
#pragma unroll
        for (int mt = 0; mt < 4; mt++)
#pragma unroll
            for (int nt = 0; nt < 4; nt++)
                acc[mt][nt] = __builtin_amdgcn_mfma_f32_16x16x32_f16(
                    af[mt], bf[nt], acc[mt][nt], 0, 0, 0);
        __syncthreads();
    }

    // epilogue: C/D layout col = lane&15, row = (lane>>4)*4 + reg
    const int erow = (lane >> 4) * 4;
    const int ecol = lane & 15;
#pragma unroll
    for (int mt = 0; mt < 4; mt++) {
#pragma unroll
        for (int r = 0; r < 4; r++) {
            const int row = m0 + wm + mt * 16 + erow + r;
#pragma unroll
            for (int nt = 0; nt < 4; nt++) {
                const int col = n0 + wn + nt * 16 + ecol;
                float v = acc[mt][nt][r];
                if (BIAS_MODE == 1) v += bias[row];
                if (BIAS_MODE == 2) v += bias[col];
                const bool valid = (col < nValid);
                const long long idx = (long long)bz * strideC + (long long)row * ldc + col;
                if (OUT_HALF) {
                    if (ZERO_PAD) {
                        ((_Float16*)Cout)[idx] = (_Float16)(valid ? v : 0.f);
                    } else if (valid) {
                        ((_Float16*)Cout)[idx] = (_Float16)v;
                    }
                } else {
                    if (ZERO_PAD) {
                        ((float*)Cout)[idx] = valid ? v : 0.f;
                    } else if (valid) {
                        ((float*)Cout)[idx] = v;
                    }
                }
            }
        }
    }
}

// ---------------------------------------------------------------------------
// row softmax: S [16*512 rows x 512] fp32 -> att fp16, one wave per row
__global__ void softmax_kernel(const float* __restrict__ S, _Float16* __restrict__ att) {
    const int row  = blockIdx.x * 4 + (threadIdx.x >> 6);
    const int lane = threadIdx.x & 63;
    const float* src = S + (long long)row * DD;
    float v[8];
#pragma unroll
    for (int i = 0; i < 8; i++) v[i] = src[lane + i * 64];
    float m = v[0];
#pragma unroll
    for (int i = 1; i < 8; i++) m = fmaxf(m, v[i]);
#pragma unroll
    for (int off = 32; off; off >>= 1) m = fmaxf(m, __shfl_xor(m, off, 64));
    float s = 0.f;
#pragma unroll
    for (int i = 0; i < 8; i++) { v[i] = __expf(v[i] - m); s += v[i]; }
#pragma unroll
    for (int off = 32; off; off >>= 1) s += __shfl_xor(s, off, 64);
    const float inv = 1.0f / s;
    _Float16* dst = att + (long long)row * DD;
#pragma unroll
    for (int i = 0; i < 8; i++) dst[lane + i * 64] = (_Float16)(v[i] * inv);
}

// ---------------------------------------------------------------------------
extern "C" void kernel_launch(void* const* d_in, const int* in_sizes, int n_in,
                              void* d_out, int out_size, void* d_ws, size_t ws_size,
                              hipStream_t stream) {
    const float* batch = (const float*)d_in[0];
    const float* Wq = (const float*)d_in[1];
    const float* bq = (const float*)d_in[2];
    const float* Wk = (const float*)d_in[3];
    const float* bk = (const float*)d_in[4];
    const float* Wv = (const float*)d_in[5];
    const float* bv = (const float*)d_in[6];

    char* ws = (char*)d_ws;
    const long long XT_B  = (long long)NB * HWP * CD * 2;      // 52,428,800
    const long long QKT_B = (long long)NB * 2 * DD * HWP * 2;  // 104,857,600
    const long long VS_B  = (long long)NB * HWP * DD * 2;      // 52,428,800
    const long long W2_B  = (long long)2 * DD * CD * 2;        // 1,048,576
    const long long WVH_B = (long long)DD * CD * 2;            // 524,288

    _Float16* Xt  = (_Float16*)(ws);
    _Float16* QKt = (_Float16*)(ws + XT_B);
    _Float16* Vs  = (_Float16*)(ws + XT_B + QKT_B);
    _Float16* W2  = (_Float16*)(ws + XT_B + QKT_B + VS_B);
    _Float16* Wvh = (_Float16*)(ws + XT_B + QKT_B + VS_B + W2_B);
    float*    b2  = (float*)   (ws + XT_B + QKT_B + VS_B + W2_B + WVH_B);
    // S and att alias the Xt region (Xt is dead after the V projection)
    float*    S   = (float*)(ws);
    _Float16* att = (_Float16*)(ws + (long long)NB * DD * DD * 4);

    // 1) weights/bias -> fp16
    convert_w_kernel<<<dim3((CD * DD + 255) / 256), dim3(256), 0, stream>>>(
        Wq, Wk, Wv, bq, bk, W2, Wvh, b2);

    // 2) batch_flat [N,C,HW] fp32 -> Xt [N,HWP,C] fp16 (zero-padded rows)
    transpose_cast_kernel<<<dim3(HWP / 64, CD / 128, NB), dim3(256), 0, stream>>>(
        batch, Xt);

    // 3) QK projection: QKt[n][m][s] = sum_c W2[m][c]*Xt[n][s][c] + b2[m]
    //    GX=8 (m), GY=25 (s), x fastest: x-blocks share the streamed Xt tile.
    gemm_tn<1, true, true, 8, 25, 0><<<dim3(8 * 25 * NB), dim3(256), 0, stream>>>(
        W2, Xt, (void*)QKt, b2, CD, HW0, HWP,
        0LL, (long long)HWP * CD, (long long)2 * DD * HWP);

    // 4) V projection: Vs[n][s][e] = sum_c Xt[n][s][c]*Wv[e][c] + bv[e]
    //    GX=25 (s), GY=4 (e), y fastest: y-blocks share the streamed Xt tile.
    gemm_tn<2, true, false, 25, 4, 1><<<dim3(25 * 4 * NB), dim3(256), 0, stream>>>(
        Xt, Wvh, (void*)Vs, bv, CD, DD, DD,
        (long long)HWP * CD, 0LL, (long long)HWP * DD);

    // 5) scores: S[n][d][e] = sum_s Qt[d][s]*Kt[e][s], K = HWP (pads are 0)
    gemm_tn<0, false, false, 4, 4, 0><<<dim3(4 * 4 * NB), dim3(256), 0, stream>>>(
        QKt, QKt + (long long)DD * HWP, (void*)S, nullptr, HWP, DD, DD,
        (long long)2 * DD * HWP, (long long)2 * DD * HWP, (long long)DD * DD);

    // 6) softmax rows -> att fp16
    softmax_kernel<<<dim3(NB * DD / 4), dim3(256), 0, stream>>>(S, att);

    // 7) out[n][d][s] = sum_e att[d][e]*Vs[n][s][e] -> d_out [N,D,HW] fp32
    //    GX=4 (d), GY=25 (s), x fastest: x-blocks share the streamed Vs tile.
    gemm_tn<0, false, false, 4, 25, 0><<<dim3(4 * 25 * NB), dim3(256), 0, stream>>>(
        att, Vs, d_out, nullptr, DD, HW0, HW0,
        (long long)DD * DD, (long long)HWP * DD, (long long)DD * HW0);
}